// Round 1
// baseline (351.637 us; speedup 1.0000x reference)
//
#include <hip/hip_runtime.h>

#define N_ 4096
#define C_ 256
#define H_ 16
#define D_ 64
#define HD_ 1024

// ---------------------------------------------------------------------------
// Kernel 1: fused projections. 4 GEMMs X[4096x256]*W[256x1024].
// Tile 128x128, 256 threads, 8x8 microtile (col-split cx*4 and cx*4+64).
// gemm 0: q = (q_x@Wq)/8 -> qh[h][n][d]
// gemm 1: k = kv_x@Wk    -> kh[h][n][d]
// gemm 2: v = kv_x@Wv    -> vh[h][n][d]
// gemm 3: g = sigmoid(q_x@Wg) -> gbuf[n][hd]
// ---------------------------------------------------------------------------
__global__ __launch_bounds__(256) void proj_kernel(
    const float* __restrict__ q_x, const float* __restrict__ kv_x,
    const float* __restrict__ Wq, const float* __restrict__ Wk,
    const float* __restrict__ Wv, const float* __restrict__ Wg,
    float* __restrict__ qh, float* __restrict__ kh,
    float* __restrict__ vh, float* __restrict__ gbuf)
{
    __shared__ float As[16][132];   // [k][m], pad 132 (stride mult of 4 floats)
    __shared__ float Bs[16][132];

    const int bid  = blockIdx.x;
    const int gemm = bid >> 8;      // 0..3
    const int tile = bid & 255;
    const int n0   = (tile >> 3) * 128;
    const int m0   = (tile & 7) * 128;

    const float* X = (gemm == 0 || gemm == 3) ? q_x : kv_x;
    const float* W = (gemm == 0) ? Wq : (gemm == 1) ? Wk : (gemm == 2) ? Wv : Wg;

    const int tid = threadIdx.x;
    const int ry  = tid >> 4;       // 0..15 -> rows ry*8..+7
    const int cx  = tid & 15;       // cols m0+cx*4+j and m0+64+cx*4+j

    const int arow = tid >> 1;           // 0..127
    const int ak0  = (tid & 1) * 8;      // 0,8
    const int bk   = tid >> 4;           // 0..15
    const int bm0  = (tid & 15) * 8;     // 0..120

    float acc[8][8];
#pragma unroll
    for (int i = 0; i < 8; ++i)
#pragma unroll
        for (int j = 0; j < 8; ++j) acc[i][j] = 0.f;

    for (int kt = 0; kt < 256; kt += 16) {
        float4 a0 = *(const float4*)(X + (size_t)(n0 + arow) * C_ + kt + ak0);
        float4 a1 = *(const float4*)(X + (size_t)(n0 + arow) * C_ + kt + ak0 + 4);
        float4 b0 = *(const float4*)(W + (size_t)(kt + bk) * HD_ + m0 + bm0);
        float4 b1 = *(const float4*)(W + (size_t)(kt + bk) * HD_ + m0 + bm0 + 4);
        __syncthreads();
        As[ak0 + 0][arow] = a0.x;
        As[ak0 + 1][arow] = a0.y;
        As[ak0 + 2][arow] = a0.z;
        As[ak0 + 3][arow] = a0.w;
        As[ak0 + 4][arow] = a1.x;
        As[ak0 + 5][arow] = a1.y;
        As[ak0 + 6][arow] = a1.z;
        As[ak0 + 7][arow] = a1.w;
        *(float4*)&Bs[bk][bm0]     = b0;
        *(float4*)&Bs[bk][bm0 + 4] = b1;
        __syncthreads();
#pragma unroll 4
        for (int k = 0; k < 16; ++k) {
            float4 av0 = *(const float4*)&As[k][ry * 8];
            float4 av1 = *(const float4*)&As[k][ry * 8 + 4];
            float4 bv0 = *(const float4*)&Bs[k][cx * 4];
            float4 bv1 = *(const float4*)&Bs[k][cx * 4 + 64];
            float av[8] = {av0.x, av0.y, av0.z, av0.w, av1.x, av1.y, av1.z, av1.w};
            float bv[8] = {bv0.x, bv0.y, bv0.z, bv0.w, bv1.x, bv1.y, bv1.z, bv1.w};
#pragma unroll
            for (int i = 0; i < 8; ++i)
#pragma unroll
                for (int j = 0; j < 8; ++j)
                    acc[i][j] += av[i] * bv[j];
        }
    }

    const int cA = m0 + cx * 4;
    const int cB = cA + 64;
    if (gemm == 3) {
#pragma unroll
        for (int i = 0; i < 8; ++i) {
            int n = n0 + ry * 8 + i;
            float4 v0, v1;
            v0.x = 1.f / (1.f + __expf(-acc[i][0]));
            v0.y = 1.f / (1.f + __expf(-acc[i][1]));
            v0.z = 1.f / (1.f + __expf(-acc[i][2]));
            v0.w = 1.f / (1.f + __expf(-acc[i][3]));
            v1.x = 1.f / (1.f + __expf(-acc[i][4]));
            v1.y = 1.f / (1.f + __expf(-acc[i][5]));
            v1.z = 1.f / (1.f + __expf(-acc[i][6]));
            v1.w = 1.f / (1.f + __expf(-acc[i][7]));
            *(float4*)&gbuf[(size_t)n * HD_ + cA] = v0;
            *(float4*)&gbuf[(size_t)n * HD_ + cB] = v1;
        }
    } else {
        const float scale = (gemm == 0) ? 0.125f : 1.f;  // 1/sqrt(64)
        float* dst = (gemm == 0) ? qh : (gemm == 1) ? kh : vh;
        const int hA = cA >> 6, dA = cA & 63;
        const int hB = cB >> 6, dB = cB & 63;
#pragma unroll
        for (int i = 0; i < 8; ++i) {
            int n = n0 + ry * 8 + i;
            float4 v0 = make_float4(acc[i][0] * scale, acc[i][1] * scale,
                                    acc[i][2] * scale, acc[i][3] * scale);
            float4 v1 = make_float4(acc[i][4] * scale, acc[i][5] * scale,
                                    acc[i][6] * scale, acc[i][7] * scale);
            *(float4*)&dst[((size_t)hA * N_ + n) * D_ + dA] = v0;
            *(float4*)&dst[((size_t)hB * N_ + n) * D_ + dB] = v1;
        }
    }
}

// ---------------------------------------------------------------------------
// Kernel 2: local attention. One block per (head h, trunk t). 256 threads.
// Trunk t: queries [t*64, t*64+64), keys at original idx [t*64-96, t*64+160).
// OOB keys/values/bias are ZERO (softmax still includes them with score 0).
// QK in two 128-key passes (8 rows x 4 cols per thread, bias = acc init);
// softmax via 32-lane shuffles; PV in four 64-key chunks through LDS;
// gate (sigmoid proj) fused into O write. LDS union: Ws overlays Qs,
// Vs overlays Ks. All float4-read rows have stride multiple of 4 floats.
// ---------------------------------------------------------------------------
__global__ __launch_bounds__(256) void attn_kernel(
    const float* __restrict__ qh, const float* __restrict__ kh,
    const float* __restrict__ vh, const float* __restrict__ bias,
    const float* __restrict__ gbuf, float* __restrict__ obuf)
{
    __shared__ float smem[64 * 68 + 64 * 132];   // 50.2 KB
    float (*Qs)[68]  = (float(*)[68])smem;               // [d][r]   phase A
    float (*Ks)[132] = (float(*)[132])(smem + 64 * 68);  // [d][s]   phase A
    float (*Ws)[68]  = (float(*)[68])smem;               // [s][r]   phase B
    float (*Vs)[64]  = (float(*)[64])(smem + 64 * 68);   // [s][d]   phase B

    const int bid = blockIdx.x;
    const int h = bid & 15;        // h fastest: 16 consecutive blocks share bias tile (L2)
    const int t = bid >> 4;
    const int tid = threadIdx.x;
    const int kbase = t * 64 - 96;

    // ---- stage Q transposed: Qs[d][r] = q[h][t*64+r][d] ----
    {
        int r  = tid >> 2;
        int d0 = (tid & 3) * 16;
        const float4* qp = (const float4*)(qh + ((size_t)h * N_ + t * 64 + r) * D_ + d0);
#pragma unroll
        for (int q = 0; q < 4; ++q) {
            float4 v = qp[q];
            int dd = d0 + q * 4;
            Qs[dd + 0][r] = v.x;
            Qs[dd + 1][r] = v.y;
            Qs[dd + 2][r] = v.z;
            Qs[dd + 3][r] = v.w;
        }
    }

    const int ry8 = (tid >> 5) * 8;   // 8 query rows per thread
    const int cxk = tid & 31;         // 4 key cols per pass

    float s[8][8];                    // scores: rows ry8+i, cols p*128+cxk*4+j

    for (int p = 0; p < 2; ++p) {
        __syncthreads();
        // stage K chunk transposed: Ks[d][sl] = k[h][kbase+p*128+sl][d], 0 if OOB
        {
            int sl = tid >> 1;
            int d0 = (tid & 1) * 32;
            int kg = kbase + p * 128 + sl;
            float4 kv4[8];
            if (kg >= 0 && kg < N_) {
                const float4* kp = (const float4*)(kh + ((size_t)h * N_ + kg) * D_ + d0);
#pragma unroll
                for (int q = 0; q < 8; ++q) kv4[q] = kp[q];
            } else {
#pragma unroll
                for (int q = 0; q < 8; ++q) kv4[q] = make_float4(0.f, 0.f, 0.f, 0.f);
            }
#pragma unroll
            for (int q = 0; q < 8; ++q) {
                int dd = d0 + q * 4;
                Ks[dd + 0][sl] = kv4[q].x;
                Ks[dd + 1][sl] = kv4[q].y;
                Ks[dd + 2][sl] = kv4[q].z;
                Ks[dd + 3][sl] = kv4[q].w;
            }
        }
        // bias as accumulator init (0 if OOB; col block is 4-aligned so all-or-none)
        {
            int colg0 = kbase + p * 128 + cxk * 4;
            bool ok = (colg0 >= 0) && (colg0 <= N_ - 4);
#pragma unroll
            for (int i = 0; i < 8; ++i) {
                float4 bv = make_float4(0.f, 0.f, 0.f, 0.f);
                if (ok) bv = *(const float4*)&bias[(size_t)(t * 64 + ry8 + i) * N_ + colg0];
                s[i][p * 4 + 0] = bv.x;
                s[i][p * 4 + 1] = bv.y;
                s[i][p * 4 + 2] = bv.z;
                s[i][p * 4 + 3] = bv.w;
            }
        }
        __syncthreads();
#pragma unroll 4
        for (int d = 0; d < 64; ++d) {
            float4 a0 = *(const float4*)&Qs[d][ry8];
            float4 a1 = *(const float4*)&Qs[d][ry8 + 4];
            float4 b  = *(const float4*)&Ks[d][cxk * 4];
            float av[8] = {a0.x, a0.y, a0.z, a0.w, a1.x, a1.y, a1.z, a1.w};
            float bw[4] = {b.x, b.y, b.z, b.w};
#pragma unroll
            for (int i = 0; i < 8; ++i)
#pragma unroll
                for (int j = 0; j < 4; ++j)
                    s[i][p * 4 + j] += av[i] * bw[j];
        }
    }

    // ---- softmax over 256 slots per row; row spread over 32 lanes (cxk) ----
#pragma unroll
    for (int i = 0; i < 8; ++i) {
        float m = s[i][0];
#pragma unroll
        for (int j = 1; j < 8; ++j) m = fmaxf(m, s[i][j]);
        for (int off = 16; off >= 1; off >>= 1) m = fmaxf(m, __shfl_xor(m, off));
        float l = 0.f;
#pragma unroll
        for (int j = 0; j < 8; ++j) { s[i][j] = __expf(s[i][j] - m); l += s[i][j]; }
        for (int off = 16; off >= 1; off >>= 1) l += __shfl_xor(l, off);
        float inv = 1.f / l;
#pragma unroll
        for (int j = 0; j < 8; ++j) s[i][j] *= inv;
    }

    // ---- PV: O[64r][64d], four 64-key chunks; W round-trips through LDS ----
    const int ryy = tid >> 4;
    const int cxx = tid & 15;
    float o[4][4];
#pragma unroll
    for (int i = 0; i < 4; ++i)
#pragma unroll
        for (int j = 0; j < 4; ++j) o[i][j] = 0.f;

    for (int c = 0; c < 4; ++c) {
        __syncthreads();   // prior Qs/Ks (c==0) or Ws/Vs reads complete
        // store this chunk's W slice: Ws[sl][r]
        if ((cxk >> 4) == (c & 1)) {
            int p4  = (c >> 1) * 4;
            int slb = cxk * 4 - (c & 1) * 64;
#pragma unroll
            for (int j = 0; j < 4; ++j)
#pragma unroll
                for (int i = 0; i < 8; ++i)
                    Ws[slb + j][ry8 + i] = s[i][p4 + j];
        }
        // stage V chunk: Vs[sl][d] = v[h][kbase+c*64+sl][d], 0 if OOB
        {
            int sl = tid >> 2;
            int d0 = (tid & 3) * 16;
            int kg = kbase + c * 64 + sl;
            float4 vv[4];
            if (kg >= 0 && kg < N_) {
                const float4* vp = (const float4*)(vh + ((size_t)h * N_ + kg) * D_ + d0);
#pragma unroll
                for (int q = 0; q < 4; ++q) vv[q] = vp[q];
            } else {
#pragma unroll
                for (int q = 0; q < 4; ++q) vv[q] = make_float4(0.f, 0.f, 0.f, 0.f);
            }
#pragma unroll
            for (int q = 0; q < 4; ++q)
                *(float4*)&Vs[sl][d0 + q * 4] = vv[q];
        }
        __syncthreads();
#pragma unroll 4
        for (int sl = 0; sl < 64; ++sl) {
            float4 a = *(const float4*)&Ws[sl][ryy * 4];
            float4 b = *(const float4*)&Vs[sl][cxx * 4];
            float aw[4] = {a.x, a.y, a.z, a.w};
            float bw[4] = {b.x, b.y, b.z, b.w};
#pragma unroll
            for (int i = 0; i < 4; ++i)
#pragma unroll
                for (int j = 0; j < 4; ++j)
                    o[i][j] += aw[i] * bw[j];
        }
    }

    // ---- gated write: obuf[n][h*64+d] = O * sigmoid-gate ----
#pragma unroll
    for (int i = 0; i < 4; ++i) {
        int n = t * 64 + ryy * 4 + i;
        int m = h * 64 + cxx * 4;
        float4 g4 = *(const float4*)&gbuf[(size_t)n * HD_ + m];
        float4 r;
        r.x = o[i][0] * g4.x;
        r.y = o[i][1] * g4.y;
        r.z = o[i][2] * g4.z;
        r.w = o[i][3] * g4.w;
        *(float4*)&obuf[(size_t)n * HD_ + m] = r;
    }
}

// ---------------------------------------------------------------------------
// Kernel 3: out = obuf[4096x1024] @ Wo[1024x256]. Tile 64x64, 4x4 microtile.
// ---------------------------------------------------------------------------
__global__ __launch_bounds__(256) void out_kernel(
    const float* __restrict__ obuf, const float* __restrict__ Wo,
    float* __restrict__ out)
{
    __shared__ float As[32][68];
    __shared__ float Bs[32][68];

    const int bid = blockIdx.x;
    const int n0 = (bid >> 2) * 64;
    const int c0 = (bid & 3) * 64;

    const int tid = threadIdx.x;
    const int ry = tid >> 4;
    const int cx = tid & 15;

    const int arow = tid >> 2;        // 0..63
    const int ak0  = (tid & 3) * 8;   // 0..24
    const int bk   = tid >> 3;        // 0..31
    const int bm0  = (tid & 7) * 8;   // 0..56

    float acc[4][4];
#pragma unroll
    for (int i = 0; i < 4; ++i)
#pragma unroll
        for (int j = 0; j < 4; ++j) acc[i][j] = 0.f;

    for (int kt = 0; kt < 1024; kt += 32) {
        float4 a0 = *(const float4*)(obuf + (size_t)(n0 + arow) * HD_ + kt + ak0);
        float4 a1 = *(const float4*)(obuf + (size_t)(n0 + arow) * HD_ + kt + ak0 + 4);
        float4 b0 = *(const float4*)(Wo + (size_t)(kt + bk) * C_ + c0 + bm0);
        float4 b1 = *(const float4*)(Wo + (size_t)(kt + bk) * C_ + c0 + bm0 + 4);
        __syncthreads();
        As[ak0 + 0][arow] = a0.x;
        As[ak0 + 1][arow] = a0.y;
        As[ak0 + 2][arow] = a0.z;
        As[ak0 + 3][arow] = a0.w;
        As[ak0 + 4][arow] = a1.x;
        As[ak0 + 5][arow] = a1.y;
        As[ak0 + 6][arow] = a1.z;
        As[ak0 + 7][arow] = a1.w;
        *(float4*)&Bs[bk][bm0]     = b0;
        *(float4*)&Bs[bk][bm0 + 4] = b1;
        __syncthreads();
#pragma unroll 8
        for (int k = 0; k < 32; ++k) {
            float4 a = *(const float4*)&As[k][ry * 4];
            float4 b = *(const float4*)&Bs[k][cx * 4];
            float aw[4] = {a.x, a.y, a.z, a.w};
            float bw[4] = {b.x, b.y, b.z, b.w};
#pragma unroll
            for (int i = 0; i < 4; ++i)
#pragma unroll
                for (int j = 0; j < 4; ++j)
                    acc[i][j] += aw[i] * bw[j];
        }
    }
#pragma unroll
    for (int i = 0; i < 4; ++i) {
        float4 r = make_float4(acc[i][0], acc[i][1], acc[i][2], acc[i][3]);
        *(float4*)&out[(size_t)(n0 + ry * 4 + i) * C_ + c0 + cx * 4] = r;
    }
}

// ---------------------------------------------------------------------------
extern "C" void kernel_launch(void* const* d_in, const int* in_sizes, int n_in,
                              void* d_out, int out_size, void* d_ws, size_t ws_size,
                              hipStream_t stream)
{
    const float* q_x  = (const float*)d_in[0];
    const float* kv_x = (const float*)d_in[1];
    const float* bias = (const float*)d_in[2];
    const float* Wq   = (const float*)d_in[3];
    const float* Wk   = (const float*)d_in[4];
    const float* Wv   = (const float*)d_in[5];
    const float* Wg   = (const float*)d_in[6];
    const float* Wo   = (const float*)d_in[7];
    float* out = (float*)d_out;

    // workspace layout: 5 x 16 MB fp32 buffers = 83.9 MB
    float* ws   = (float*)d_ws;
    const size_t SEG = (size_t)4194304;       // 16*4096*64 = 4096*1024
    float* qh   = ws;                         // [H][N][D], pre-scaled by 1/8
    float* kh   = ws + SEG;                   // [H][N][D]
    float* vh   = ws + 2 * SEG;               // [H][N][D]
    float* gbuf = ws + 3 * SEG;               // [N][HD] sigmoid gate
    float* obuf = ws + 4 * SEG;               // [N][HD] gated attention out

    proj_kernel<<<1024, 256, 0, stream>>>(q_x, kv_x, Wq, Wk, Wv, Wg, qh, kh, vh, gbuf);
    attn_kernel<<<1024, 256, 0, stream>>>(qh, kh, vh, bias, gbuf, obuf);
    out_kernel<<<256, 256, 0, stream>>>(obuf, Wo, out);
}

// Round 3
// 260.640 us; speedup vs baseline: 1.3491x; 1.3491x over previous
//
#include <hip/hip_runtime.h>

#define N_ 4096
#define C_ 256
#define H_ 16
#define D_ 64
#define HD_ 1024

typedef __attribute__((ext_vector_type(8))) __bf16 bf16x8;
typedef __attribute__((ext_vector_type(4))) __bf16 bf16x4;
typedef __attribute__((ext_vector_type(4))) float f32x4;

__device__ __forceinline__ void gload16(const void* g, void* l) {
    __builtin_amdgcn_global_load_lds(
        (const __attribute__((address_space(1))) unsigned int*)g,
        (__attribute__((address_space(3))) unsigned int*)l, 16, 0, 0);
}

// hi/lo split: hi = bf16(v), lo = bf16(v - hi). (Cannot pass vector elements
// by reference — return via struct.)
struct bf2 { __bf16 h, l; };
__device__ __forceinline__ bf2 split_bf16(float v) {
    bf2 r;
    r.h = (__bf16)v;
    r.l = (__bf16)(v - (float)r.h);
    return r;
}

// ---------------------------------------------------------------------------
// Kernel 0: convert fp32 inputs to bf16 hi/lo (X as-is, W transposed so the
// MFMA B-operand reads K-contiguous). Blocks:
//   [0,512):   q_x / kv_x elementwise -> Xh/Xl [2][4096][256]
//   [512,768): Wq..Wg [256][1024] -> WTh/WTl [4][1024][256] (transposed)
//   [768,832): Wo [1024][256] -> WoTh/WoTl [256][1024] (transposed)
// ---------------------------------------------------------------------------
__global__ __launch_bounds__(256) void convert_kernel(
    const float* __restrict__ q_x, const float* __restrict__ kv_x,
    const float* __restrict__ Wq, const float* __restrict__ Wk,
    const float* __restrict__ Wv, const float* __restrict__ Wg,
    const float* __restrict__ Wo,
    __bf16* __restrict__ Xh, __bf16* __restrict__ Xl,
    __bf16* __restrict__ WTh, __bf16* __restrict__ WTl,
    __bf16* __restrict__ WoTh, __bf16* __restrict__ WoTl)
{
    __shared__ float ts[64][65];
    const int b = blockIdx.x;
    const int tid = threadIdx.x;

    if (b < 512) {
        const int seg = b >> 8;
        const float* src = seg ? kv_x : q_x;
        __bf16* dh = Xh + (size_t)seg * 1048576;
        __bf16* dl = Xl + (size_t)seg * 1048576;
        const int base = (b & 255) * 4096 + tid * 16;
#pragma unroll
        for (int q = 0; q < 4; ++q) {
            float4 v = *(const float4*)&src[base + q * 4];
            bf16x4 hv, lv;
            bf2 s0 = split_bf16(v.x); hv[0] = s0.h; lv[0] = s0.l;
            bf2 s1 = split_bf16(v.y); hv[1] = s1.h; lv[1] = s1.l;
            bf2 s2 = split_bf16(v.z); hv[2] = s2.h; lv[2] = s2.l;
            bf2 s3 = split_bf16(v.w); hv[3] = s3.h; lv[3] = s3.l;
            *(bf16x4*)&dh[base + q * 4] = hv;
            *(bf16x4*)&dl[base + q * 4] = lv;
        }
        return;
    }

    // transpose path: read 64x64 tile of src [R][srcC] at (r0,c0),
    // write dst [srcC][R] (dstC = R)
    const float* src;
    __bf16 *dh, *dl;
    int srcC, dstC, r0, c0;
    if (b < 768) {
        const int widx = (b - 512) >> 6;
        const int tile = (b - 512) & 63;
        src = (widx == 0) ? Wq : (widx == 1) ? Wk : (widx == 2) ? Wv : Wg;
        dh = WTh + (size_t)widx * 262144;
        dl = WTl + (size_t)widx * 262144;
        srcC = 1024; dstC = 256;
        r0 = (tile >> 4) * 64;      // 0..3  (rows of 256)
        c0 = (tile & 15) * 64;      // 0..15 (cols of 1024)
    } else {
        const int tile = b - 768;
        src = Wo; dh = WoTh; dl = WoTl;
        srcC = 256; dstC = 1024;
        r0 = (tile >> 2) * 64;      // 0..15 (rows of 1024)
        c0 = (tile & 3) * 64;       // 0..3  (cols of 256)
    }
    {
        const int r = tid >> 2;
        const int cch = (tid & 3) * 16;
#pragma unroll
        for (int q = 0; q < 4; ++q) {
            float4 v = *(const float4*)&src[(size_t)(r0 + r) * srcC + c0 + cch + q * 4];
            ts[r][cch + q * 4 + 0] = v.x;
            ts[r][cch + q * 4 + 1] = v.y;
            ts[r][cch + q * 4 + 2] = v.z;
            ts[r][cch + q * 4 + 3] = v.w;
        }
    }
    __syncthreads();
    {
        const int c = tid >> 2;
        const int rch = (tid & 3) * 16;
#pragma unroll
        for (int q = 0; q < 4; ++q) {
            bf16x4 hv, lv;
#pragma unroll
            for (int j = 0; j < 4; ++j) {
                bf2 s = split_bf16(ts[rch + q * 4 + j][c]);
                hv[j] = s.h; lv[j] = s.l;
            }
            *(bf16x4*)&dh[(size_t)(c0 + c) * dstC + r0 + rch + q * 4] = hv;
            *(bf16x4*)&dl[(size_t)(c0 + c) * dstC + r0 + rch + q * 4] = lv;
        }
    }
}

// ---------------------------------------------------------------------------
// Kernel 1: projections via split-bf16 MFMA. 4 GEMMs M=4096,N=1024,K=256.
// 128x128 tile, 4 waves (2x2), each wave 4x4 frags of 16x16x32.
// acc += Ah*Bh + Ah*Bl + Al*Bh (3-term split, ~fp32 accuracy).
// global->LDS via global_load_lds width 16 (m97 structure).
// ---------------------------------------------------------------------------
__global__ __launch_bounds__(256) void proj_mfma(
    const __bf16* __restrict__ Xh, const __bf16* __restrict__ Xl,
    const __bf16* __restrict__ WTh, const __bf16* __restrict__ WTl,
    float* __restrict__ qh, float* __restrict__ kh,
    float* __restrict__ vh, float* __restrict__ gbuf)
{
    __shared__ __align__(16) __bf16 smem[4 * 4096];   // As_h, As_l, Bs_h, Bs_l (8KB each)
    __bf16* As_h = smem;
    __bf16* As_l = smem + 4096;
    __bf16* Bs_h = smem + 8192;
    __bf16* Bs_l = smem + 12288;

    const int bid  = blockIdx.x;
    const int g    = bid >> 8;              // gemm 0..3
    const int tile = bid & 255;
    const int m0   = (tile >> 3) * 128;     // token rows
    const int c0   = (tile & 7) * 128;      // feature cols

    const size_t xoff = (g == 1 || g == 2) ? 1048576 : 0;
    const __bf16* Ah = Xh + xoff;
    const __bf16* Al = Xl + xoff;
    const __bf16* Bh = WTh + (size_t)g * 262144;
    const __bf16* Bl = WTl + (size_t)g * 262144;

    const int tid  = threadIdx.x;
    const int wave = tid >> 6;
    const int lane = tid & 63;
    const int wr   = wave >> 1;
    const int wc   = wave & 1;

    // staging: thread's 16B chunk p covers LDS linear byte p*4096 + tid*16
    const int srow = tid >> 2;              // 0..63
    const int selem = (tid & 3) * 8;        // k-element offset 0,8,16,24
    const int sbyte = tid * 16;             // LDS byte offset (pass 0)

    f32x4 acc[4][4];
#pragma unroll
    for (int i = 0; i < 4; ++i)
#pragma unroll
        for (int j = 0; j < 4; ++j) acc[i][j] = (f32x4){0.f, 0.f, 0.f, 0.f};

    const int frow = lane & 15;
    const int fk   = (lane >> 4) * 8;

    for (int kt = 0; kt < 256; kt += 32) {
        __syncthreads();
#pragma unroll
        for (int p = 0; p < 2; ++p) {
            const int r = srow + p * 64;
            gload16(Ah + (size_t)(m0 + r) * 256 + kt + selem, (char*)As_h + p * 4096 + sbyte);
            gload16(Al + (size_t)(m0 + r) * 256 + kt + selem, (char*)As_l + p * 4096 + sbyte);
            gload16(Bh + (size_t)(c0 + r) * 256 + kt + selem, (char*)Bs_h + p * 4096 + sbyte);
            gload16(Bl + (size_t)(c0 + r) * 256 + kt + selem, (char*)Bs_l + p * 4096 + sbyte);
        }
        __syncthreads();

        bf16x8 afh[4], afl[4], bfh[4], bfl[4];
#pragma unroll
        for (int f = 0; f < 4; ++f) {
            const int ar = (wr * 64 + f * 16 + frow) * 32 + fk;
            const int br = (wc * 64 + f * 16 + frow) * 32 + fk;
            afh[f] = *(const bf16x8*)&As_h[ar];
            afl[f] = *(const bf16x8*)&As_l[ar];
            bfh[f] = *(const bf16x8*)&Bs_h[br];
            bfl[f] = *(const bf16x8*)&Bs_l[br];
        }
#pragma unroll
        for (int i = 0; i < 4; ++i)
#pragma unroll
            for (int j = 0; j < 4; ++j) {
                acc[i][j] = __builtin_amdgcn_mfma_f32_16x16x32_bf16(afh[i], bfh[j], acc[i][j], 0, 0, 0);
                acc[i][j] = __builtin_amdgcn_mfma_f32_16x16x32_bf16(afl[i], bfh[j], acc[i][j], 0, 0, 0);
                acc[i][j] = __builtin_amdgcn_mfma_f32_16x16x32_bf16(afh[i], bfl[j], acc[i][j], 0, 0, 0);
            }
    }

    // epilogue: C/D layout col=lane&15, row=(lane>>4)*4+reg  [m89]
    const int rbase = (lane >> 4) * 4;
    const int colc  = lane & 15;
    if (g == 3) {
#pragma unroll
        for (int i = 0; i < 4; ++i)
#pragma unroll
            for (int j = 0; j < 4; ++j) {
                const int c = c0 + wc * 64 + j * 16 + colc;
#pragma unroll
                for (int v = 0; v < 4; ++v) {
                    const int n = m0 + wr * 64 + i * 16 + rbase + v;
                    gbuf[(size_t)n * HD_ + c] = 1.f / (1.f + __expf(-acc[i][j][v]));
                }
            }
    } else {
        const float scale = (g == 0) ? 0.125f : 1.f;
        float* dst = (g == 0) ? qh : (g == 1) ? kh : vh;
#pragma unroll
        for (int i = 0; i < 4; ++i)
#pragma unroll
            for (int j = 0; j < 4; ++j) {
                const int c = c0 + wc * 64 + j * 16 + colc;
                const int hh = c >> 6, dd = c & 63;
#pragma unroll
                for (int v = 0; v < 4; ++v) {
                    const int n = m0 + wr * 64 + i * 16 + rbase + v;
                    dst[((size_t)hh * N_ + n) * D_ + dd] = acc[i][j][v] * scale;
                }
            }
    }
}

// ---------------------------------------------------------------------------
// Kernel 2: local attention (fp32, unchanged math). One block per (h,t).
// Epilogue now emits gated output as bf16 hi/lo for the MFMA out-GEMM.
// ---------------------------------------------------------------------------
__global__ __launch_bounds__(256) void attn_kernel(
    const float* __restrict__ qh, const float* __restrict__ kh,
    const float* __restrict__ vh, const float* __restrict__ bias,
    const float* __restrict__ gbuf,
    __bf16* __restrict__ o_hi, __bf16* __restrict__ o_lo)
{
    __shared__ float smem[64 * 68 + 64 * 132];   // 50.2 KB
    float (*Qs)[68]  = (float(*)[68])smem;               // [d][r]   phase A
    float (*Ks)[132] = (float(*)[132])(smem + 64 * 68);  // [d][s]   phase A
    float (*Ws)[68]  = (float(*)[68])smem;               // [s][r]   phase B
    float (*Vs)[64]  = (float(*)[64])(smem + 64 * 68);   // [s][d]   phase B

    const int bid = blockIdx.x;
    const int h = bid & 15;
    const int t = bid >> 4;
    const int tid = threadIdx.x;
    const int kbase = t * 64 - 96;

    {
        int r  = tid >> 2;
        int d0 = (tid & 3) * 16;
        const float4* qp = (const float4*)(qh + ((size_t)h * N_ + t * 64 + r) * D_ + d0);
#pragma unroll
        for (int q = 0; q < 4; ++q) {
            float4 v = qp[q];
            int dd = d0 + q * 4;
            Qs[dd + 0][r] = v.x;
            Qs[dd + 1][r] = v.y;
            Qs[dd + 2][r] = v.z;
            Qs[dd + 3][r] = v.w;
        }
    }

    const int ry8 = (tid >> 5) * 8;
    const int cxk = tid & 31;

    float s[8][8];

    for (int p = 0; p < 2; ++p) {
        __syncthreads();
        {
            int sl = tid >> 1;
            int d0 = (tid & 1) * 32;
            int kg = kbase + p * 128 + sl;
            float4 kv4[8];
            if (kg >= 0 && kg < N_) {
                const float4* kp = (const float4*)(kh + ((size_t)h * N_ + kg) * D_ + d0);
#pragma unroll
                for (int q = 0; q < 8; ++q) kv4[q] = kp[q];
            } else {
#pragma unroll
                for (int q = 0; q < 8; ++q) kv4[q] = make_float4(0.f, 0.f, 0.f, 0.f);
            }
#pragma unroll
            for (int q = 0; q < 8; ++q) {
                int dd = d0 + q * 4;
                Ks[dd + 0][sl] = kv4[q].x;
                Ks[dd + 1][sl] = kv4[q].y;
                Ks[dd + 2][sl] = kv4[q].z;
                Ks[dd + 3][sl] = kv4[q].w;
            }
        }
        {
            int colg0 = kbase + p * 128 + cxk * 4;
            bool ok = (colg0 >= 0) && (colg0 <= N_ - 4);
#pragma unroll
            for (int i = 0; i < 8; ++i) {
                float4 bv = make_float4(0.f, 0.f, 0.f, 0.f);
                if (ok) bv = *(const float4*)&bias[(size_t)(t * 64 + ry8 + i) * N_ + colg0];
                s[i][p * 4 + 0] = bv.x;
                s[i][p * 4 + 1] = bv.y;
                s[i][p * 4 + 2] = bv.z;
                s[i][p * 4 + 3] = bv.w;
            }
        }
        __syncthreads();
#pragma unroll 4
        for (int d = 0; d < 64; ++d) {
            float4 a0 = *(const float4*)&Qs[d][ry8];
            float4 a1 = *(const float4*)&Qs[d][ry8 + 4];
            float4 b  = *(const float4*)&Ks[d][cxk * 4];
            float av[8] = {a0.x, a0.y, a0.z, a0.w, a1.x, a1.y, a1.z, a1.w};
            float bw[4] = {b.x, b.y, b.z, b.w};
#pragma unroll
            for (int i = 0; i < 8; ++i)
#pragma unroll
                for (int j = 0; j < 4; ++j)
                    s[i][p * 4 + j] += av[i] * bw[j];
        }
    }

#pragma unroll
    for (int i = 0; i < 8; ++i) {
        float m = s[i][0];
#pragma unroll
        for (int j = 1; j < 8; ++j) m = fmaxf(m, s[i][j]);
        for (int off = 16; off >= 1; off >>= 1) m = fmaxf(m, __shfl_xor(m, off));
        float l = 0.f;
#pragma unroll
        for (int j = 0; j < 8; ++j) { s[i][j] = __expf(s[i][j] - m); l += s[i][j]; }
        for (int off = 16; off >= 1; off >>= 1) l += __shfl_xor(l, off);
        float inv = 1.f / l;
#pragma unroll
        for (int j = 0; j < 8; ++j) s[i][j] *= inv;
    }

    const int ryy = tid >> 4;
    const int cxx = tid & 15;
    float o[4][4];
#pragma unroll
    for (int i = 0; i < 4; ++i)
#pragma unroll
        for (int j = 0; j < 4; ++j) o[i][j] = 0.f;

    for (int c = 0; c < 4; ++c) {
        __syncthreads();
        if ((cxk >> 4) == (c & 1)) {
            int p4  = (c >> 1) * 4;
            int slb = cxk * 4 - (c & 1) * 64;
#pragma unroll
            for (int j = 0; j < 4; ++j)
#pragma unroll
                for (int i = 0; i < 8; ++i)
                    Ws[slb + j][ry8 + i] = s[i][p4 + j];
        }
        {
            int sl = tid >> 2;
            int d0 = (tid & 3) * 16;
            int kg = kbase + c * 64 + sl;
            float4 vv[4];
            if (kg >= 0 && kg < N_) {
                const float4* vp = (const float4*)(vh + ((size_t)h * N_ + kg) * D_ + d0);
#pragma unroll
                for (int q = 0; q < 4; ++q) vv[q] = vp[q];
            } else {
#pragma unroll
                for (int q = 0; q < 4; ++q) vv[q] = make_float4(0.f, 0.f, 0.f, 0.f);
            }
#pragma unroll
            for (int q = 0; q < 4; ++q)
                *(float4*)&Vs[sl][d0 + q * 4] = vv[q];
        }
        __syncthreads();
#pragma unroll 4
        for (int sl = 0; sl < 64; ++sl) {
            float4 a = *(const float4*)&Ws[sl][ryy * 4];
            float4 b = *(const float4*)&Vs[sl][cxx * 4];
            float aw[4] = {a.x, a.y, a.z, a.w};
            float bw[4] = {b.x, b.y, b.z, b.w};
#pragma unroll
            for (int i = 0; i < 4; ++i)
#pragma unroll
                for (int j = 0; j < 4; ++j)
                    o[i][j] += aw[i] * bw[j];
        }
    }

#pragma unroll
    for (int i = 0; i < 4; ++i) {
        int n = t * 64 + ryy * 4 + i;
        int m = h * 64 + cxx * 4;
        float4 g4 = *(const float4*)&gbuf[(size_t)n * HD_ + m];
        float vals[4] = {o[i][0] * g4.x, o[i][1] * g4.y, o[i][2] * g4.z, o[i][3] * g4.w};
        bf16x4 hv, lv;
#pragma unroll
        for (int j = 0; j < 4; ++j) {
            bf2 s2 = split_bf16(vals[j]);
            hv[j] = s2.h; lv[j] = s2.l;
        }
        *(bf16x4*)&o_hi[(size_t)n * HD_ + m] = hv;
        *(bf16x4*)&o_lo[(size_t)n * HD_ + m] = lv;
    }
}

// ---------------------------------------------------------------------------
// Kernel 3: out = (o*g)[4096x1024] @ Wo[1024x256] via split-bf16 MFMA.
// Tile 128x64, 4 waves (2x2), wave = 64x32 (4x2 frags). K=1024, BK=32.
// ---------------------------------------------------------------------------
__global__ __launch_bounds__(256) void out_mfma(
    const __bf16* __restrict__ o_hi, const __bf16* __restrict__ o_lo,
    const __bf16* __restrict__ WoTh, const __bf16* __restrict__ WoTl,
    float* __restrict__ out)
{
    __shared__ __align__(16) __bf16 smem[2 * 4096 + 2 * 2048];  // A 8KB x2, B 4KB x2
    __bf16* As_h = smem;
    __bf16* As_l = smem + 4096;
    __bf16* Bs_h = smem + 8192;
    __bf16* Bs_l = smem + 10240;

    const int bid = blockIdx.x;
    const int m0  = (bid >> 2) * 128;
    const int c0  = (bid & 3) * 64;

    const int tid  = threadIdx.x;
    const int wave = tid >> 6;
    const int lane = tid & 63;
    const int wr   = wave >> 1;
    const int wc   = wave & 1;

    const int srow  = tid >> 2;
    const int selem = (tid & 3) * 8;
    const int sbyte = tid * 16;

    f32x4 acc[4][2];
#pragma unroll
    for (int i = 0; i < 4; ++i)
#pragma unroll
        for (int j = 0; j < 2; ++j) acc[i][j] = (f32x4){0.f, 0.f, 0.f, 0.f};

    const int frow = lane & 15;
    const int fk   = (lane >> 4) * 8;

    for (int kt = 0; kt < 1024; kt += 32) {
        __syncthreads();
#pragma unroll
        for (int p = 0; p < 2; ++p) {
            const int r = srow + p * 64;
            gload16(o_hi + (size_t)(m0 + r) * HD_ + kt + selem, (char*)As_h + p * 4096 + sbyte);
            gload16(o_lo + (size_t)(m0 + r) * HD_ + kt + selem, (char*)As_l + p * 4096 + sbyte);
        }
        gload16(WoTh + (size_t)(c0 + srow) * HD_ + kt + selem, (char*)Bs_h + sbyte);
        gload16(WoTl + (size_t)(c0 + srow) * HD_ + kt + selem, (char*)Bs_l + sbyte);
        __syncthreads();

        bf16x8 afh[4], afl[4], bfh[2], bfl[2];
#pragma unroll
        for (int f = 0; f < 4; ++f) {
            const int ar = (wr * 64 + f * 16 + frow) * 32 + fk;
            afh[f] = *(const bf16x8*)&As_h[ar];
            afl[f] = *(const bf16x8*)&As_l[ar];
        }
#pragma unroll
        for (int f = 0; f < 2; ++f) {
            const int br = (wc * 32 + f * 16 + frow) * 32 + fk;
            bfh[f] = *(const bf16x8*)&Bs_h[br];
            bfl[f] = *(const bf16x8*)&Bs_l[br];
        }
#pragma unroll
        for (int i = 0; i < 4; ++i)
#pragma unroll
            for (int j = 0; j < 2; ++j) {
                acc[i][j] = __builtin_amdgcn_mfma_f32_16x16x32_bf16(afh[i], bfh[j], acc[i][j], 0, 0, 0);
                acc[i][j] = __builtin_amdgcn_mfma_f32_16x16x32_bf16(afl[i], bfh[j], acc[i][j], 0, 0, 0);
                acc[i][j] = __builtin_amdgcn_mfma_f32_16x16x32_bf16(afh[i], bfl[j], acc[i][j], 0, 0, 0);
            }
    }

    const int rbase = (lane >> 4) * 4;
    const int colc  = lane & 15;
#pragma unroll
    for (int i = 0; i < 4; ++i)
#pragma unroll
        for (int j = 0; j < 2; ++j) {
            const int c = c0 + wc * 32 + j * 16 + colc;
#pragma unroll
            for (int v = 0; v < 4; ++v) {
                const int n = m0 + wr * 64 + i * 16 + rbase + v;
                out[(size_t)n * C_ + c] = acc[i][j][v];
            }
        }
}

// ---------------------------------------------------------------------------
extern "C" void kernel_launch(void* const* d_in, const int* in_sizes, int n_in,
                              void* d_out, int out_size, void* d_ws, size_t ws_size,
                              hipStream_t stream)
{
    const float* q_x  = (const float*)d_in[0];
    const float* kv_x = (const float*)d_in[1];
    const float* bias = (const float*)d_in[2];
    const float* Wq   = (const float*)d_in[3];
    const float* Wk   = (const float*)d_in[4];
    const float* Wv   = (const float*)d_in[5];
    const float* Wg   = (const float*)d_in[6];
    const float* Wo   = (const float*)d_in[7];
    float* out = (float*)d_out;

    // workspace layout (93 MB):
    char* ws = (char*)d_ws;
    float*  qh   = (float*)(ws);                         // [16][4096][64] f32, pre-scaled 1/8
    float*  kh   = (float*)(ws + (size_t)16 * 1048576);
    float*  vh   = (float*)(ws + (size_t)32 * 1048576);
    float*  gbuf = (float*)(ws + (size_t)48 * 1048576);  // [4096][1024] f32
    __bf16* o_hi = (__bf16*)(ws + (size_t)64 * 1048576); // [4096][1024] bf16
    __bf16* o_lo = (__bf16*)(ws + (size_t)72 * 1048576);
    __bf16* Xh   = (__bf16*)(ws + (size_t)80 * 1048576); // [2][4096][256]
    __bf16* Xl   = (__bf16*)(ws + (size_t)84 * 1048576);
    __bf16* WTh  = (__bf16*)(ws + (size_t)88 * 1048576); // [4][1024][256]
    __bf16* WTl  = (__bf16*)(ws + (size_t)90 * 1048576);
    __bf16* WoTh = (__bf16*)(ws + (size_t)92 * 1048576); // [256][1024]
    __bf16* WoTl = (__bf16*)(ws + (size_t)92 * 1048576 + 524288);

    convert_kernel<<<832, 256, 0, stream>>>(q_x, kv_x, Wq, Wk, Wv, Wg, Wo,
                                            Xh, Xl, WTh, WTl, WoTh, WoTl);
    proj_mfma<<<1024, 256, 0, stream>>>(Xh, Xl, WTh, WTl, qh, kh, vh, gbuf);
    attn_kernel<<<1024, 256, 0, stream>>>(qh, kh, vh, bias, gbuf, o_hi, o_lo);
    out_mfma<<<128, 256, 0, stream>>>(o_hi, o_lo, WoTh, WoTl, out);
}

// Round 4
// 196.019 us; speedup vs baseline: 1.7939x; 1.3297x over previous
//
#include <hip/hip_runtime.h>

#define N_ 4096
#define C_ 256
#define H_ 16
#define D_ 64
#define HD_ 1024

typedef __attribute__((ext_vector_type(8))) __bf16 bf16x8;
typedef __attribute__((ext_vector_type(4))) __bf16 bf16x4;
typedef __attribute__((ext_vector_type(8))) _Float16 f16x8;
typedef __attribute__((ext_vector_type(4))) float f32x4;

__device__ __forceinline__ void gload16(const void* g, void* l) {
    __builtin_amdgcn_global_load_lds(
        (const __attribute__((address_space(1))) unsigned int*)g,
        (__attribute__((address_space(3))) unsigned int*)l, 16, 0, 0);
}

struct bf2 { __bf16 h, l; };
__device__ __forceinline__ bf2 split_bf16(float v) {
    bf2 r;
    r.h = (__bf16)v;
    r.l = (__bf16)(v - (float)r.h);
    return r;
}

// ---------------------------------------------------------------------------
// Kernel 0: convert fp32 inputs to bf16 hi/lo (X as-is, W transposed so the
// MFMA B-operand reads K-contiguous).
// ---------------------------------------------------------------------------
__global__ __launch_bounds__(256) void convert_kernel(
    const float* __restrict__ q_x, const float* __restrict__ kv_x,
    const float* __restrict__ Wq, const float* __restrict__ Wk,
    const float* __restrict__ Wv, const float* __restrict__ Wg,
    const float* __restrict__ Wo,
    __bf16* __restrict__ Xh, __bf16* __restrict__ Xl,
    __bf16* __restrict__ WTh, __bf16* __restrict__ WTl,
    __bf16* __restrict__ WoTh, __bf16* __restrict__ WoTl)
{
    __shared__ float ts[64][65];
    const int b = blockIdx.x;
    const int tid = threadIdx.x;

    if (b < 512) {
        const int seg = b >> 8;
        const float* src = seg ? kv_x : q_x;
        __bf16* dh = Xh + (size_t)seg * 1048576;
        __bf16* dl = Xl + (size_t)seg * 1048576;
        const int base = (b & 255) * 4096 + tid * 16;
#pragma unroll
        for (int q = 0; q < 4; ++q) {
            float4 v = *(const float4*)&src[base + q * 4];
            bf16x4 hv, lv;
            bf2 s0 = split_bf16(v.x); hv[0] = s0.h; lv[0] = s0.l;
            bf2 s1 = split_bf16(v.y); hv[1] = s1.h; lv[1] = s1.l;
            bf2 s2 = split_bf16(v.z); hv[2] = s2.h; lv[2] = s2.l;
            bf2 s3 = split_bf16(v.w); hv[3] = s3.h; lv[3] = s3.l;
            *(bf16x4*)&dh[base + q * 4] = hv;
            *(bf16x4*)&dl[base + q * 4] = lv;
        }
        return;
    }

    const float* src;
    __bf16 *dh, *dl;
    int srcC, dstC, r0, c0;
    if (b < 768) {
        const int widx = (b - 512) >> 6;
        const int tile = (b - 512) & 63;
        src = (widx == 0) ? Wq : (widx == 1) ? Wk : (widx == 2) ? Wv : Wg;
        dh = WTh + (size_t)widx * 262144;
        dl = WTl + (size_t)widx * 262144;
        srcC = 1024; dstC = 256;
        r0 = (tile >> 4) * 64;
        c0 = (tile & 15) * 64;
    } else {
        const int tile = b - 768;
        src = Wo; dh = WoTh; dl = WoTl;
        srcC = 256; dstC = 1024;
        r0 = (tile >> 2) * 64;
        c0 = (tile & 3) * 64;
    }
    {
        const int r = tid >> 2;
        const int cch = (tid & 3) * 16;
#pragma unroll
        for (int q = 0; q < 4; ++q) {
            float4 v = *(const float4*)&src[(size_t)(r0 + r) * srcC + c0 + cch + q * 4];
            ts[r][cch + q * 4 + 0] = v.x;
            ts[r][cch + q * 4 + 1] = v.y;
            ts[r][cch + q * 4 + 2] = v.z;
            ts[r][cch + q * 4 + 3] = v.w;
        }
    }
    __syncthreads();
    {
        const int c = tid >> 2;
        const int rch = (tid & 3) * 16;
#pragma unroll
        for (int q = 0; q < 4; ++q) {
            bf16x4 hv, lv;
#pragma unroll
            for (int j = 0; j < 4; ++j) {
                bf2 s = split_bf16(ts[rch + q * 4 + j][c]);
                hv[j] = s.h; lv[j] = s.l;
            }
            *(bf16x4*)&dh[(size_t)(c0 + c) * dstC + r0 + rch + q * 4] = hv;
            *(bf16x4*)&dl[(size_t)(c0 + c) * dstC + r0 + rch + q * 4] = lv;
        }
    }
}

// ---------------------------------------------------------------------------
// Kernel 1: projections via split-bf16 MFMA. Epilogue now emits fp16:
// qh/kh/vh [h][n][d] fp16 (q pre-scaled 1/8), gh [n][hd] fp16 (sigmoid).
// ---------------------------------------------------------------------------
__global__ __launch_bounds__(256) void proj_mfma(
    const __bf16* __restrict__ Xh, const __bf16* __restrict__ Xl,
    const __bf16* __restrict__ WTh, const __bf16* __restrict__ WTl,
    _Float16* __restrict__ qh, _Float16* __restrict__ kh,
    _Float16* __restrict__ vh, _Float16* __restrict__ gh)
{
    __shared__ __align__(16) __bf16 smem[4 * 4096];
    __bf16* As_h = smem;
    __bf16* As_l = smem + 4096;
    __bf16* Bs_h = smem + 8192;
    __bf16* Bs_l = smem + 12288;

    const int bid  = blockIdx.x;
    const int g    = bid >> 8;
    const int tile = bid & 255;
    const int m0   = (tile >> 3) * 128;
    const int c0   = (tile & 7) * 128;

    const size_t xoff = (g == 1 || g == 2) ? 1048576 : 0;
    const __bf16* Ah = Xh + xoff;
    const __bf16* Al = Xl + xoff;
    const __bf16* Bh = WTh + (size_t)g * 262144;
    const __bf16* Bl = WTl + (size_t)g * 262144;

    const int tid  = threadIdx.x;
    const int wave = tid >> 6;
    const int lane = tid & 63;
    const int wr   = wave >> 1;
    const int wc   = wave & 1;

    const int srow = tid >> 2;
    const int selem = (tid & 3) * 8;
    const int sbyte = tid * 16;

    f32x4 acc[4][4];
#pragma unroll
    for (int i = 0; i < 4; ++i)
#pragma unroll
        for (int j = 0; j < 4; ++j) acc[i][j] = (f32x4){0.f, 0.f, 0.f, 0.f};

    const int frow = lane & 15;
    const int fk   = (lane >> 4) * 8;

    for (int kt = 0; kt < 256; kt += 32) {
        __syncthreads();
#pragma unroll
        for (int p = 0; p < 2; ++p) {
            const int r = srow + p * 64;
            gload16(Ah + (size_t)(m0 + r) * 256 + kt + selem, (char*)As_h + p * 4096 + sbyte);
            gload16(Al + (size_t)(m0 + r) * 256 + kt + selem, (char*)As_l + p * 4096 + sbyte);
            gload16(Bh + (size_t)(c0 + r) * 256 + kt + selem, (char*)Bs_h + p * 4096 + sbyte);
            gload16(Bl + (size_t)(c0 + r) * 256 + kt + selem, (char*)Bs_l + p * 4096 + sbyte);
        }
        __syncthreads();

        bf16x8 afh[4], afl[4], bfh[4], bfl[4];
#pragma unroll
        for (int f = 0; f < 4; ++f) {
            const int ar = (wr * 64 + f * 16 + frow) * 32 + fk;
            const int br = (wc * 64 + f * 16 + frow) * 32 + fk;
            afh[f] = *(const bf16x8*)&As_h[ar];
            afl[f] = *(const bf16x8*)&As_l[ar];
            bfh[f] = *(const bf16x8*)&Bs_h[br];
            bfl[f] = *(const bf16x8*)&Bs_l[br];
        }
#pragma unroll
        for (int i = 0; i < 4; ++i)
#pragma unroll
            for (int j = 0; j < 4; ++j) {
                acc[i][j] = __builtin_amdgcn_mfma_f32_16x16x32_bf16(afh[i], bfh[j], acc[i][j], 0, 0, 0);
                acc[i][j] = __builtin_amdgcn_mfma_f32_16x16x32_bf16(afl[i], bfh[j], acc[i][j], 0, 0, 0);
                acc[i][j] = __builtin_amdgcn_mfma_f32_16x16x32_bf16(afh[i], bfl[j], acc[i][j], 0, 0, 0);
            }
    }

    const int rbase = (lane >> 4) * 4;
    const int colc  = lane & 15;
    if (g == 3) {
#pragma unroll
        for (int i = 0; i < 4; ++i)
#pragma unroll
            for (int j = 0; j < 4; ++j) {
                const int c = c0 + wc * 64 + j * 16 + colc;
#pragma unroll
                for (int v = 0; v < 4; ++v) {
                    const int n = m0 + wr * 64 + i * 16 + rbase + v;
                    gh[(size_t)n * HD_ + c] = (_Float16)(1.f / (1.f + __expf(-acc[i][j][v])));
                }
            }
    } else {
        const float scale = (g == 0) ? 0.125f : 1.f;
        _Float16* dst = (g == 0) ? qh : (g == 1) ? kh : vh;
#pragma unroll
        for (int i = 0; i < 4; ++i)
#pragma unroll
            for (int j = 0; j < 4; ++j) {
                const int c = c0 + wc * 64 + j * 16 + colc;
                const int hh = c >> 6, dd = c & 63;
#pragma unroll
                for (int v = 0; v < 4; ++v) {
                    const int n = m0 + wr * 64 + i * 16 + rbase + v;
                    dst[((size_t)hh * N_ + n) * D_ + dd] = (_Float16)(acc[i][j][v] * scale);
                }
            }
    }
}

// ---------------------------------------------------------------------------
// Kernel 2: local attention via fp16 MFMA. One block per (h,t), 4 waves.
// Wave w owns S rows w*16..w*16+16, all 256 key slots.
// Q/K staged by global_load_lds with XOR chunk swizzle (conflict-free b128).
// Bias = accumulator init (OOB -> 0, zero-pad semantics). Softmax in regs
// (unnormalized exp -> Ps; 1/l folded into epilogue). V transposed to LDS
// for the PV B-operand. Epilogue: *inv, *gate, write o bf16 hi/lo.
// ---------------------------------------------------------------------------
__global__ __launch_bounds__(256) void attn_mfma(
    const _Float16* __restrict__ qh, const _Float16* __restrict__ kh,
    const _Float16* __restrict__ vh, const float* __restrict__ bias,
    const _Float16* __restrict__ gh,
    __bf16* __restrict__ o_hi, __bf16* __restrict__ o_lo)
{
    __shared__ __align__(16) char smem[59392];
    _Float16* Qs = (_Float16*)smem;              // [64][64], swizzled chunks, 8 KB
    char* Ks = smem + 8192;                      // K: [128][64] swizzled, 16 KB
    _Float16* Vs = (_Float16*)(smem + 8192);     // V^T: [64][136], 17408 B (overlays Ks)
    _Float16* Ps = (_Float16*)(smem + 25600);    // [64][264], 33792 B

    const int bid = blockIdx.x;
    const int h = bid & 15;
    const int t = bid >> 4;
    const int tid = threadIdx.x;
    const int lane = tid & 63;
    const int wv = tid >> 6;
    const int frow = lane & 15;
    const int grp = lane >> 4;
    const int kbase = t * 64 - 96;

    const char* qbase = (const char*)qh + (size_t)(h * N_ + t * 64) * 128;
    const char* kbase_p = (const char*)kh + (size_t)h * N_ * 128;

    // ---- stage Q (8 KB, always in-bounds), issue async ----
#pragma unroll
    for (int q = 0; q < 2; ++q) {
        const int lin = q * 4096 + tid * 16;
        const int row = lin >> 7;
        const int ch = (lin >> 4) & 7;
        gload16(qbase + row * 128 + ((ch ^ (row & 7)) << 4), (char*)Qs + lin);
    }

    f32x4 sacc[16];

#pragma unroll
    for (int p = 0; p < 2; ++p) {
        // stage K chunk p (16 KB); OOB rows -> zero (wave-uniform split)
#pragma unroll
        for (int q = 0; q < 4; ++q) {
            const int lin = q * 4096 + tid * 16;
            const int row = lin >> 7;
            const int ch = (lin >> 4) & 7;
            const int kg = kbase + p * 128 + row;
            if ((unsigned)kg < (unsigned)N_) {
                gload16(kbase_p + (size_t)kg * 128 + ((ch ^ (row & 7)) << 4), Ks + lin);
            } else {
                *(float4*)(Ks + lin) = make_float4(0.f, 0.f, 0.f, 0.f);
            }
        }
        // bias -> accumulator init for this chunk
        {
            const int rowg = t * 64 + wv * 16 + grp * 4;
#pragma unroll
            for (int j = 0; j < 8; ++j) {
                const int colg = kbase + p * 128 + j * 16 + frow;
                const bool ok = (unsigned)colg < (unsigned)N_;
#pragma unroll
                for (int v = 0; v < 4; ++v)
                    sacc[p * 8 + j][v] = ok ? bias[(size_t)(rowg + v) * N_ + colg] : 0.f;
            }
        }
        __syncthreads();   // staging complete (Q covered at p=0)
        const int rq = wv * 16 + frow;
#pragma unroll
        for (int ks = 0; ks < 2; ++ks) {
            const f16x8 aq = *(const f16x8*)((char*)Qs + rq * 128 + (((ks * 4 + grp) ^ (rq & 7)) << 4));
#pragma unroll
            for (int j = 0; j < 8; ++j) {
                const int rk = j * 16 + frow;
                const f16x8 bk = *(const f16x8*)(Ks + rk * 128 + (((ks * 4 + grp) ^ (rk & 7)) << 4));
                sacc[p * 8 + j] = __builtin_amdgcn_mfma_f32_16x16x32_f16(aq, bk, sacc[p * 8 + j], 0, 0, 0);
            }
        }
        __syncthreads();   // K reads done before restage/overlay
    }

    // ---- softmax over 256 slots/row; rows owned per (grp, v) ----
    float inv[4];
#pragma unroll
    for (int v = 0; v < 4; ++v) {
        float m = sacc[0][v];
#pragma unroll
        for (int f = 1; f < 16; ++f) m = fmaxf(m, sacc[f][v]);
        m = fmaxf(m, __shfl_xor(m, 1));
        m = fmaxf(m, __shfl_xor(m, 2));
        m = fmaxf(m, __shfl_xor(m, 4));
        m = fmaxf(m, __shfl_xor(m, 8));
        float l = 0.f;
#pragma unroll
        for (int f = 0; f < 16; ++f) {
            float e = __expf(sacc[f][v] - m);
            sacc[f][v] = e;
            l += e;
        }
        l += __shfl_xor(l, 1);
        l += __shfl_xor(l, 2);
        l += __shfl_xor(l, 4);
        l += __shfl_xor(l, 8);
        inv[v] = 1.f / l;
    }

    // ---- write unnormalized P (fp16) to LDS ----
    {
        const int rb = wv * 16 + grp * 4;
#pragma unroll
        for (int f = 0; f < 16; ++f) {
            const int col = (f >> 3) * 128 + (f & 7) * 16 + frow;
#pragma unroll
            for (int v = 0; v < 4; ++v)
                Ps[(rb + v) * 264 + col] = (_Float16)sacc[f][v];
        }
    }

    // ---- PV: O[64 rows][64 d] over 2 slot-chunks of 128; V^T staged in LDS ----
    f32x4 oacc[4];
#pragma unroll
    for (int jd = 0; jd < 4; ++jd) oacc[jd] = (f32x4){0.f, 0.f, 0.f, 0.f};

#pragma unroll
    for (int c = 0; c < 2; ++c) {
        // stage V^T chunk: Vs[d][sl] (prior barrier guarantees Ks/Vs free)
        {
            const int sl = tid >> 1;
            const int d0 = (tid & 1) * 32;
            const int kg = kbase + c * 128 + sl;
            f16x8 vv[4];
            if ((unsigned)kg < (unsigned)N_) {
                const f16x8* vp = (const f16x8*)(vh + ((size_t)h * N_ + kg) * D_ + d0);
#pragma unroll
                for (int q = 0; q < 4; ++q) vv[q] = vp[q];
            } else {
#pragma unroll
                for (int q = 0; q < 4; ++q)
#pragma unroll
                    for (int e = 0; e < 8; ++e) vv[q][e] = (_Float16)0.f;
            }
#pragma unroll
            for (int q = 0; q < 4; ++q)
#pragma unroll
                for (int e = 0; e < 8; ++e)
                    Vs[(d0 + q * 8 + e) * 136 + sl] = vv[q][e];
        }
        __syncthreads();   // Ps (c==0) + Vs ready
        const int rp = wv * 16 + frow;
#pragma unroll
        for (int ks = 0; ks < 4; ++ks) {
            const f16x8 ap = *(const f16x8*)((char*)Ps + rp * 528 + c * 256 + ks * 64 + grp * 16);
#pragma unroll
            for (int jd = 0; jd < 4; ++jd) {
                const f16x8 bv = *(const f16x8*)((char*)Vs + (jd * 16 + frow) * 272 + ks * 64 + grp * 16);
                oacc[jd] = __builtin_amdgcn_mfma_f32_16x16x32_f16(ap, bv, oacc[jd], 0, 0, 0);
            }
        }
        __syncthreads();   // Vs reads done before restage
    }

    // ---- epilogue: O * inv * gate -> bf16 hi/lo ----
#pragma unroll
    for (int jd = 0; jd < 4; ++jd) {
        const int dcol = jd * 16 + frow;
        const int cg = h * 64 + dcol;
#pragma unroll
        for (int v = 0; v < 4; ++v) {
            const int n = t * 64 + wv * 16 + grp * 4 + v;
            const float gt = (float)gh[(size_t)n * HD_ + cg];
            const float val = oacc[jd][v] * inv[v] * gt;
            bf2 s = split_bf16(val);
            o_hi[(size_t)n * HD_ + cg] = s.h;
            o_lo[(size_t)n * HD_ + cg] = s.l;
        }
    }
}

// ---------------------------------------------------------------------------
// Kernel 3: out = (o*g)[4096x1024] @ Wo[1024x256] via split-bf16 MFMA.
// Tile 64x64 (256 blocks -> all CUs), 4 waves 2x2, wave 32x32 (2x2 frags).
// ---------------------------------------------------------------------------
__global__ __launch_bounds__(256) void out_mfma(
    const __bf16* __restrict__ o_hi, const __bf16* __restrict__ o_lo,
    const __bf16* __restrict__ WoTh, const __bf16* __restrict__ WoTl,
    float* __restrict__ out)
{
    __shared__ __align__(16) __bf16 smem[4 * 2048];  // As_h, As_l, Bs_h, Bs_l (4 KB each)
    __bf16* As_h = smem;
    __bf16* As_l = smem + 2048;
    __bf16* Bs_h = smem + 4096;
    __bf16* Bs_l = smem + 6144;

    const int bid = blockIdx.x;
    const int m0  = (bid >> 2) * 64;
    const int c0  = (bid & 3) * 64;

    const int tid  = threadIdx.x;
    const int wave = tid >> 6;
    const int lane = tid & 63;
    const int wr   = wave >> 1;
    const int wc   = wave & 1;

    const int srow  = tid >> 2;        // 0..63
    const int selem = (tid & 3) * 8;   // 0..24
    const int sbyte = tid * 16;

    f32x4 acc[2][2];
#pragma unroll
    for (int i = 0; i < 2; ++i)
#pragma unroll
        for (int j = 0; j < 2; ++j) acc[i][j] = (f32x4){0.f, 0.f, 0.f, 0.f};

    const int frow = lane & 15;
    const int fk   = (lane >> 4) * 8;

    for (int kt = 0; kt < 1024; kt += 32) {
        __syncthreads();
        gload16(o_hi + (size_t)(m0 + srow) * HD_ + kt + selem, (char*)As_h + sbyte);
        gload16(o_lo + (size_t)(m0 + srow) * HD_ + kt + selem, (char*)As_l + sbyte);
        gload16(WoTh + (size_t)(c0 + srow) * HD_ + kt + selem, (char*)Bs_h + sbyte);
        gload16(WoTl + (size_t)(c0 + srow) * HD_ + kt + selem, (char*)Bs_l + sbyte);
        __syncthreads();

        bf16x8 afh[2], afl[2], bfh[2], bfl[2];
#pragma unroll
        for (int f = 0; f < 2; ++f) {
            const int ar = (wr * 32 + f * 16 + frow) * 32 + fk;
            const int br = (wc * 32 + f * 16 + frow) * 32 + fk;
            afh[f] = *(const bf16x8*)&As_h[ar];
            afl[f] = *(const bf16x8*)&As_l[ar];
            bfh[f] = *(const bf16x8*)&Bs_h[br];
            bfl[f] = *(const bf16x8*)&Bs_l[br];
        }
#pragma unroll
        for (int i = 0; i < 2; ++i)
#pragma unroll
            for (int j = 0; j < 2; ++j) {
                acc[i][j] = __builtin_amdgcn_mfma_f32_16x16x32_bf16(afh[i], bfh[j], acc[i][j], 0, 0, 0);
                acc[i][j] = __builtin_amdgcn_mfma_f32_16x16x32_bf16(afl[i], bfh[j], acc[i][j], 0, 0, 0);
                acc[i][j] = __builtin_amdgcn_mfma_f32_16x16x32_bf16(afh[i], bfl[j], acc[i][j], 0, 0, 0);
            }
    }

    const int rbase = (lane >> 4) * 4;
    const int colc  = lane & 15;
#pragma unroll
    for (int i = 0; i < 2; ++i)
#pragma unroll
        for (int j = 0; j < 2; ++j) {
            const int c = c0 + wc * 32 + j * 16 + colc;
#pragma unroll
            for (int v = 0; v < 4; ++v) {
                const int n = m0 + wr * 32 + i * 16 + rbase + v;
                out[(size_t)n * C_ + c] = acc[i][j][v];
            }
        }
}

// ---------------------------------------------------------------------------
extern "C" void kernel_launch(void* const* d_in, const int* in_sizes, int n_in,
                              void* d_out, int out_size, void* d_ws, size_t ws_size,
                              hipStream_t stream)
{
    const float* q_x  = (const float*)d_in[0];
    const float* kv_x = (const float*)d_in[1];
    const float* bias = (const float*)d_in[2];
    const float* Wq   = (const float*)d_in[3];
    const float* Wk   = (const float*)d_in[4];
    const float* Wv   = (const float*)d_in[5];
    const float* Wg   = (const float*)d_in[6];
    const float* Wo   = (const float*)d_in[7];
    float* out = (float*)d_out;

    // workspace layout (61 MB)
    char* ws = (char*)d_ws;
    const size_t MB = 1048576;
    _Float16* qh  = (_Float16*)(ws);             // [16][4096][64] fp16, pre-scaled 1/8
    _Float16* kh  = (_Float16*)(ws + 8  * MB);
    _Float16* vh  = (_Float16*)(ws + 16 * MB);
    _Float16* gh  = (_Float16*)(ws + 24 * MB);   // [4096][1024] fp16 sigmoid gate
    __bf16* o_hi  = (__bf16*)(ws + 32 * MB);     // [4096][1024] bf16
    __bf16* o_lo  = (__bf16*)(ws + 40 * MB);
    __bf16* Xh    = (__bf16*)(ws + 48 * MB);     // [2][4096][256]
    __bf16* Xl    = (__bf16*)(ws + 52 * MB);
    __bf16* WTh   = (__bf16*)(ws + 56 * MB);     // [4][1024][256]
    __bf16* WTl   = (__bf16*)(ws + 58 * MB);
    __bf16* WoTh  = (__bf16*)(ws + 60 * MB);     // [256][1024]
    __bf16* WoTl  = (__bf16*)(ws + 60 * MB + 524288);

    convert_kernel<<<832, 256, 0, stream>>>(q_x, kv_x, Wq, Wk, Wv, Wg, Wo,
                                            Xh, Xl, WTh, WTl, WoTh, WoTl);
    proj_mfma<<<1024, 256, 0, stream>>>(Xh, Xl, WTh, WTl, qh, kh, vh, gh);
    attn_mfma<<<1024, 256, 0, stream>>>(qh, kh, vh, bias, gh, o_hi, o_lo);
    out_mfma<<<256, 256, 0, stream>>>(o_hi, o_lo, WoTh, WoTl, out);
}